// Round 8
// baseline (194.266 us; speedup 1.0000x reference)
//
#include <hip/hip_runtime.h>

// SynthesisStage: modulated conv2d w/ adaptive kernel selection.
// B=8, Ci=Co=256, H=W=128, K=3, N=4.
// v8 = v7 + VALU/address trims:
//  - PFB via 3 precomputed per-lane bases + ds_read offset immediates
//    (n*1024 step is swizzle-invariant: +16 w = +8 rows, row&7 unchanged)
//  - zero guard rows (w' = w+2; rows 0 and 65 zeroed once) -> branchless PFB
//  - x pack: +0x8000 round-half-up + v_perm_b32 (3 VALU/pair vs ~10)
// Pipeline identical to v7: A-frags direct global->VGPR (dbuf), XR dbuf in
// LDS, 1 raw s_barrier per (dh,kb) group, compiler-counted vmcnt.

typedef __attribute__((ext_vector_type(4))) float f32x4;
typedef __attribute__((ext_vector_type(8))) short s16x8;

#define NB   8
#define NCI  256
#define NCO  256
#define NHW  128
#define NKER 4
#define XRS  8448    // XR buf stride: 66 rows x 128B (rows 0,65 = zero guards)

#define SB0 __builtin_amdgcn_sched_barrier(0)
#define BAR __builtin_amdgcn_s_barrier()
#define WAITL0 asm volatile("s_waitcnt lgkmcnt(0)" ::: "memory")

__device__ __forceinline__ unsigned short f2bf(float f) {
  unsigned int u = __builtin_bit_cast(unsigned int, f);
  u += 0x7FFFu + ((u >> 16) & 1u);          // round-to-nearest-even
  return (unsigned short)(u >> 16);
}

// ---------------------------------------------------------------------------
// Kernel 1: modulated+demodulated weights -> bf16 in FRAGMENT-DIRECT order.
// Tile T=(b*9+tap)*8+kb is 16KB; conv_k wave wid reads af[m] as one coalesced
// dwordx4 at T*16384 + wid*4096 + m*1024 + lane*16.  (unchanged from v7)
// ---------------------------------------------------------------------------
__global__ __launch_bounds__(256) void prep_k(
    const float* __restrict__ weight,    // [N][Co][Ci][3][3]
    const float* __restrict__ styles,    // [B][Ci]
    const float* __restrict__ selector,  // [B][N]
    unsigned short* __restrict__ wmod)   // fragment-ordered, 9.44 MB
{
  int bid = blockIdx.x;
  int b = bid >> 8, co = bid & 255;
  int ci = threadIdx.x;

  float sel[NKER];
#pragma unroll
  for (int n = 0; n < NKER; ++n) sel[n] = selector[b * NKER + n];

  float a[9];
#pragma unroll
  for (int j = 0; j < 9; ++j) a[j] = 0.f;
#pragma unroll
  for (int n = 0; n < NKER; ++n) {
    const float* wp = weight + (size_t)((n * NCO + co) * NCI + ci) * 9;
    float s = sel[n];
#pragma unroll
    for (int j = 0; j < 9; ++j) a[j] += s * wp[j];
  }
  float st = styles[b * NCI + ci];
  float ss = 0.f;
#pragma unroll
  for (int j = 0; j < 9; ++j) { a[j] *= st; ss += a[j] * a[j]; }

  for (int off = 32; off; off >>= 1) ss += __shfl_down(ss, off, 64);
  __shared__ float red[4];
  int wid = threadIdx.x >> 6, lane = threadIdx.x & 63;
  if (lane == 0) red[wid] = ss;
  __syncthreads();
  float tot = red[0] + red[1] + red[2] + red[3];
  float d = rsqrtf(tot + 1e-8f);

  int kb = ci >> 5;
  size_t base = (size_t)(co >> 4) * 512 +
                (size_t)(((ci & 31) >> 3) * 128) + ((co & 15) * 8) + (ci & 7);
#pragma unroll
  for (int j = 0; j < 9; ++j) {
    size_t T = (size_t)((b * 9 + j) * 8 + kb);
    wmod[(T << 13) + base] = f2bf(a[j] * d);
  }
}

// ---------------------------------------------------------------------------
// Kernel 2: implicit-GEMM conv; A direct-from-global, B via LDS dbuf w/ guards.
// block = (b, h); 256 thr = 4 waves, wave tile 64co x 128px; 72 K-tiles.
// XR value (w,ci'): w'=w+2, row=w'>>1, slot=(((w'&1)<<2)+(ci'>>3))^(row&7),
// byte = row*128 + slot*16 + (ci'&7)*2.
// ---------------------------------------------------------------------------
__global__ __launch_bounds__(256, 2) void conv_k(
    const float* __restrict__ x,              // [B][Ci][H][W] f32
    const unsigned short* __restrict__ wg,    // fragment-ordered wmod
    const float* __restrict__ noise,          // [B][Co][H][W]
    float* __restrict__ out)                  // [B][Co][H][W]
{
  extern __shared__ __align__(16) char XRs[]; // 2 x 8448B XR dbuf (w/ guards)

  int orig = blockIdx.x;             // 1024 blocks
  int b = orig & 7;                  // XCD-resident sample
  int h = orig >> 3;

  int t = threadIdx.x;
  int lane = t & 63;
  int wid = t >> 6;
  int cow = wid << 6;
  int ll = lane & 15;
  int ks = lane >> 4;                // k-slice 0..3

  f32x4 acc[4][8];
#pragma unroll
  for (int m = 0; m < 4; ++m)
#pragma unroll
    for (int n = 0; n < 8; ++n) acc[m][n] = (f32x4){0.f, 0.f, 0.f, 0.f};

  // --- precomputed PFB bases: one per dw; n-th frag = base + n*1024 ---
  int bofs[3];
#pragma unroll
  for (int dw = 0; dw < 3; ++dw) {
    int w0 = ll + dw + 1;            // w' at n=0
    int row0 = w0 >> 1;
    int slot0 = (((w0 & 1) << 2) + ks) ^ (row0 & 7);
    bofs[dw] = row0 * 128 + slot0 * 16;
  }

  // --- pack mapping: thread owns ci-pair (c,c+1) x 16 w (w = wi + 16*j2) ---
  int c = ((t >> 4) & 15) * 2;
  int wi = t & 15;
  int prow = (wi + 2) >> 1;
  int pslot = (((wi & 1) << 2) + (c >> 3)) ^ (prow & 7);
  int pbase = prow * 128 + pslot * 16 + ((c & 7) << 1);
  float xlo[8], xhi[8];
  int hvalid = 1;

  auto issueX = [&](int g) {
    int gc = g < 24 ? g : 23;
    int dh = gc >> 3, kb = gc & 7;
    int hy = h + dh - 1;
    hvalid = ((unsigned)hy < 128u);
    int hyc = hy < 0 ? 0 : (hy > 127 ? 127 : hy);
    const float* base = x + ((size_t)(b * NCI + kb * 32 + c) * NHW + hyc) * NHW + wi;
#pragma unroll
    for (int j2 = 0; j2 < 8; ++j2) {
      xlo[j2] = base[j2 * 16];
      xhi[j2] = base[NHW * NHW + j2 * 16];
    }
  };

  auto issueAF = [&](int tc, s16x8* af) {
    if (tc > 71) tc = 71;
    int g = tc / 3, tap = tc - g * 3;
    int dh = g >> 3, kb = g & 7;
    const char* src = (const char*)wg +
        ((size_t)((b * 9 + dh * 3 + tap) * 8 + kb) << 14) + wid * 4096 + lane * 16;
#pragma unroll
    for (int m = 0; m < 4; ++m)
      af[m] = *(const s16x8*)(src + m * 1024);
  };

  auto packXR = [&](int g) {
    char* p0 = XRs + (g & 1) * XRS + pbase;
    if (hvalid) {
#pragma unroll
      for (int j2 = 0; j2 < 8; ++j2) {
        unsigned uhi = __builtin_bit_cast(unsigned, xhi[j2]) + 0x8000u;
        unsigned ulo = __builtin_bit_cast(unsigned, xlo[j2]) + 0x8000u;
        *(unsigned*)(p0 + j2 * 1024) = __builtin_amdgcn_perm(uhi, ulo, 0x07060302u);
      }
    } else {
#pragma unroll
      for (int j2 = 0; j2 < 8; ++j2)
        *(unsigned*)(p0 + j2 * 1024) = 0u;
    }
  };

// B-fragments: branchless, base + literal offsets (guard rows cover edges)
#define PFB(BUFIMM, DW, bf)                                              \
  {                                                                      \
    const char* Xb = XRs + bofs[DW] + (BUFIMM);                          \
    _Pragma("unroll")                                                    \
    for (int n = 0; n < 8; ++n)                                          \
      bf[n] = *(const s16x8*)(Xb + n * 1024);                            \
  }

#define MFMA32(af, bf)                                                   \
  __builtin_amdgcn_s_setprio(1);                                         \
  _Pragma("unroll")                                                      \
  for (int m = 0; m < 4; ++m)                                            \
    _Pragma("unroll")                                                    \
    for (int n = 0; n < 8; ++n)                                          \
      acc[m][n] = __builtin_amdgcn_mfma_f32_16x16x32_bf16(               \
          af[m], bf[n], acc[m][n], 0, 0, 0);                             \
  __builtin_amdgcn_s_setprio(0);

  s16x8 afA[4], afB[4], bf[8];

  // ---- prologue: zero guard rows; x(0); af(0); pack XR(0) ----
  if (t < 32) {                       // 4 guard rows x 128B = 32 x 16B
    int rg = t >> 3;                  // {buf0 r0, buf0 r65, buf1 r0, buf1 r65}
    char* gz = XRs + (rg >> 1) * XRS + ((rg & 1) ? 65 * 128 : 0) + (t & 7) * 16;
    *(f32x4*)gz = (f32x4){0.f, 0.f, 0.f, 0.f};
  }
  issueX(0); SB0;
  issueAF(0, afA); SB0;
  packXR(0);                          // compiler waits x via counted vmcnt

  // ---- main loop: 12 x 6 tiles (2 groups); 1 barrier per group ----
#pragma unroll 1
  for (int gg = 0; gg < 12; ++gg) {
    int g0 = gg * 2, t0 = gg * 6;
    // T0: group g0 (xr buf0), tap0, af=afA
    WAITL0; SB0; BAR; SB0;
    PFB(0, 0, bf);
    issueAF(t0 + 1, afB); SB0;
    issueX(g0 + 1); SB0;
    MFMA32(afA, bf);
    // T1: tap1, af=afB
    PFB(0, 1, bf);
    issueAF(t0 + 2, afA); SB0;
    MFMA32(afB, bf);
    // T2: tap2, af=afA
    PFB(0, 2, bf);
    issueAF(t0 + 3, afB); SB0;
    packXR(g0 + 1);
    MFMA32(afA, bf);
    // T3: group g0+1 (xr buf1), tap0, af=afB
    WAITL0; SB0; BAR; SB0;
    PFB(XRS, 0, bf);
    issueAF(t0 + 4, afA); SB0;
    issueX(g0 + 2); SB0;
    MFMA32(afB, bf);
    // T4: tap1, af=afA
    PFB(XRS, 1, bf);
    issueAF(t0 + 5, afB); SB0;
    MFMA32(afA, bf);
    // T5: tap2, af=afB
    PFB(XRS, 2, bf);
    issueAF(t0 + 6, afA); SB0;
    packXR(g0 + 2);
    MFMA32(afB, bf);
  }

  // epilogue: D[row=ks*4+j][col=ll], fused noise add
  int pr4 = ks * 4;
#pragma unroll
  for (int m = 0; m < 4; ++m) {
#pragma unroll
    for (int n = 0; n < 8; ++n) {
      int px = n * 16 + ll;
#pragma unroll
      for (int j = 0; j < 4; ++j) {
        int co = cow + m * 16 + pr4 + j;
        size_t idx = ((size_t)(b * NCO + co) * NHW + h) * NHW + px;
        out[idx] = acc[m][n][j] + noise[idx];
      }
    }
  }
}

// ---------------------------------------------------------------------------
extern "C" void kernel_launch(void* const* d_in, const int* in_sizes, int n_in,
                              void* d_out, int out_size, void* d_ws, size_t ws_size,
                              hipStream_t stream) {
  const float* x        = (const float*)d_in[0];
  const float* weight   = (const float*)d_in[1];
  const float* styles   = (const float*)d_in[2];
  const float* selector = (const float*)d_in[3];
  const float* noise    = (const float*)d_in[4];
  float* out = (float*)d_out;

  // workspace: ONLY wmod (fragment-ordered) = 9,437,184 bytes
  unsigned short* wmod = (unsigned short*)d_ws;

  hipLaunchKernelGGL(prep_k, dim3(NB * NCO), dim3(256), 0, stream,
                     weight, styles, selector, wmod);
  hipLaunchKernelGGL(conv_k, dim3(NB * NHW), dim3(256), 2 * XRS, stream,
                     x, wmod, noise, out);
}